// Round 1
// baseline (204.746 us; speedup 1.0000x reference)
//
#include <hip/hip_runtime.h>

// SpectralRewiringLayer. Factorized: h1 = relu(u[src] + v[dst]),
//   u[n] = W1[0:64]^T emb[n] + b1 + fied[n]*W1[128]
//   v[n] = W1[64:128]^T emb[n] + fied[n]*W1[129]
// fp16 storage for u,v. K1 unchanged (transposed MFMA GEMM).
//
// R4: edge_mlp was gather-LATENCY bound (MfmaUtil 8%, VALU 32%, HBM 38%,
// 0.17 lines/cyc/CU ~= ~80 in-flight lines / ~450cyc avg latency).
// New: 2-D counting sort of edges into 64 (src-slice x dst-slice) buckets;
// slices of n/8 nodes so u-slice (1.6MB) + v-slice (1.6MB) fit one XCD's
// 4MB private L2. Records packed u64 (src17|dst17|eid30), src-slice-major
// so each XCD (bid&7 heuristic) owns a contiguous range and its u-slice
// stays L2-resident. Predicted: avg gather latency ~450->~250cyc.

#define HD 64

typedef __attribute__((ext_vector_type(8))) _Float16 half8;
typedef __attribute__((ext_vector_type(4))) _Float16 half4;
typedef __attribute__((ext_vector_type(8))) short  short8;
typedef __attribute__((ext_vector_type(8))) float  float8;
typedef __attribute__((ext_vector_type(4))) float  f32x4;

__device__ __forceinline__ half8 relu_h8(half8 x) {
    short8 b = __builtin_bit_cast(short8, x);
    short8 m = b >> 15;
    b = b & ~m;
    return __builtin_bit_cast(half8, b);
}

// ---------------- K1: u,v precompute, transposed MFMA GEMM ----------------
__global__ __launch_bounds__(256) void precompute_uv(
    const float* __restrict__ emb, const float* __restrict__ fied,
    const float* __restrict__ W1, const float* __restrict__ b1,
    _Float16* __restrict__ u, _Float16* __restrict__ v,
    int n_nodes, int ntiles)
{
    const int lane = threadIdx.x & 63;
    const int q = lane >> 4;
    const int c = lane & 15;
    const int wid = blockIdx.x * (blockDim.x >> 6) + (threadIdx.x >> 6);
    const int nw  = gridDim.x * (blockDim.x >> 6);

    half8 Au[4][2], Av[4][2];
    #pragma unroll
    for (int t = 0; t < 4; ++t)
        #pragma unroll
        for (int ks = 0; ks < 2; ++ks)
            #pragma unroll
            for (int j = 0; j < 8; ++j) {
                int k = ks * 32 + q * 8 + j;
                Au[t][ks][j] = (_Float16)W1[k * HD + t * 16 + c];
                Av[t][ks][j] = (_Float16)W1[(64 + k) * HD + t * 16 + c];
            }
    f32x4 b1q[4], wsq[4], wdq[4];
    #pragma unroll
    for (int t = 0; t < 4; ++t) {
        b1q[t] = *(const f32x4*)(b1 + t * 16 + q * 4);
        wsq[t] = *(const f32x4*)(W1 + 128 * HD + t * 16 + q * 4);
        wdq[t] = *(const f32x4*)(W1 + 129 * HD + t * 16 + q * 4);
    }

    for (int tile = wid; tile < ntiles; tile += nw) {
        const int n0 = tile * 16;
        const int n  = n0 + c;
        int na = n; if (na >= n_nodes) na = n_nodes - 1;
        const float* rp = emb + (size_t)na * HD + q * 8;
        float8 a0 = *(const float8*)rp;
        float8 a1 = *(const float8*)(rp + 32);
        half8 B0 = __builtin_convertvector(a0, half8);
        half8 B1 = __builtin_convertvector(a1, half8);

        f32x4 aU[4] = {}, aV[4] = {};
        #pragma unroll
        for (int t = 0; t < 4; ++t) {
            aU[t] = __builtin_amdgcn_mfma_f32_16x16x32_f16(Au[t][0], B0, aU[t], 0, 0, 0);
            aU[t] = __builtin_amdgcn_mfma_f32_16x16x32_f16(Au[t][1], B1, aU[t], 0, 0, 0);
            aV[t] = __builtin_amdgcn_mfma_f32_16x16x32_f16(Av[t][0], B0, aV[t], 0, 0, 0);
            aV[t] = __builtin_amdgcn_mfma_f32_16x16x32_f16(Av[t][1], B1, aV[t], 0, 0, 0);
        }

        const float fv = fied[na];
        const bool ok = (n < n_nodes);
        #pragma unroll
        for (int t = 0; t < 4; ++t) {
            half4 hu, hv;
            #pragma unroll
            for (int r = 0; r < 4; ++r) {
                hu[r] = (_Float16)(aU[t][r] + b1q[t][r] + fv * wsq[t][r]);
                hv[r] = (_Float16)(aV[t][r] + fv * wdq[t][r]);
            }
            if (ok) {
                *(half4*)(u + (size_t)n * HD + t * 16 + q * 4) = hu;
                *(half4*)(v + (size_t)n * HD + t * 16 + q * 4) = hv;
            }
        }
    }
}

// ---------------- fallback K2 (ws too small): per-edge MLP ----------------
__global__ __launch_bounds__(256) void edge_mlp(
    const _Float16* __restrict__ u, const _Float16* __restrict__ v,
    const int* __restrict__ src, const int* __restrict__ dst,
    const float* __restrict__ W2, const float* __restrict__ b2,
    const float* __restrict__ W3, const float* __restrict__ b3,
    float* __restrict__ out, int E, int ntiles)
{
    const int lane = threadIdx.x & 63;
    const int q = lane >> 4;
    const int c = lane & 15;
    const int wid = blockIdx.x * (blockDim.x >> 6) + (threadIdx.x >> 6);
    const int nw  = gridDim.x * (blockDim.x >> 6);

    half8 Af[4][2];
    #pragma unroll
    for (int t = 0; t < 4; ++t)
        #pragma unroll
        for (int ks = 0; ks < 2; ++ks)
            #pragma unroll
            for (int j = 0; j < 8; ++j) {
                int k = ks * 32 + q * 8 + j;
                Af[t][ks][j] = (_Float16)W2[k * HD + t * 16 + c];
            }
    f32x4 b2q[4], w3q[4];
    #pragma unroll
    for (int t = 0; t < 4; ++t) {
        b2q[t] = *(const f32x4*)(b2 + t * 16 + q * 4);
        w3q[t] = *(const f32x4*)(W3 + t * 16 + q * 4);
    }
    const float b3v = b3[0];

    const int stride = nw * 2;
    const int base0  = wid * 2;

    auto eid = [&](int tile) {
        int t = tile; if (t >= ntiles) t = ntiles - 1;
        int e = t * 16 + c; if (e >= E) e = E - 1;
        return e;
    };
    auto issue = [&](int s, int d, half8& Ua, half8& Ub, half8& Va, half8& Vb) {
        const half8* up = (const half8*)(u + (unsigned)s * HD + q * 8);
        const half8* vp = (const half8*)(v + (unsigned)d * HD + q * 8);
        Ua = up[0]; Ub = up[4]; Va = vp[0]; Vb = vp[4];
    };
    auto compute_store = [&](int tile, half8 Ua, half8 Ub, half8 Va, half8 Vb) {
        half8 B0 = relu_h8(Ua + Va);
        half8 B1 = relu_h8(Ub + Vb);
        f32x4 acc[4];
        #pragma unroll
        for (int t = 0; t < 4; ++t) acc[t] = b2q[t];
        #pragma unroll
        for (int t = 0; t < 4; ++t) {
            acc[t] = __builtin_amdgcn_mfma_f32_16x16x32_f16(Af[t][0], B0, acc[t], 0, 0, 0);
            acc[t] = __builtin_amdgcn_mfma_f32_16x16x32_f16(Af[t][1], B1, acc[t], 0, 0, 0);
        }
        float p = 0.f;
        #pragma unroll
        for (int t = 0; t < 4; ++t)
            #pragma unroll
            for (int r = 0; r < 4; ++r)
                p = fmaf(fmaxf(acc[t][r], 0.f), w3q[t][r], p);
        p += __shfl_xor(p, 16, 64);
        p += __shfl_xor(p, 32, 64);
        if (q == 0) {
            int e = tile * 16 + c;
            if (e < E) out[e] = p + b3v;
        }
    };

    if (base0 >= ntiles) return;

    int e0 = eid(base0), e1 = eid(base0 + 1);
    int s0 = src[e0], d0 = dst[e0];
    int s1 = src[e1], d1 = dst[e1];
    half8 U0a, U0b, V0a, V0b, U1a, U1b, V1a, V1b;
    issue(s0, d0, U0a, U0b, V0a, V0b);
    issue(s1, d1, U1a, U1b, V1a, V1b);
    int e2 = eid(base0 + stride), e3 = eid(base0 + stride + 1);
    int sc0 = src[e2], dc0 = dst[e2];
    int sc1 = src[e3], dc1 = dst[e3];

    for (int base = base0; base < ntiles; base += stride) {
        const int f0 = eid(base + 2 * stride), f1 = eid(base + 2 * stride + 1);
        const int sn0 = src[f0], dn0 = dst[f0];
        const int sn1 = src[f1], dn1 = dst[f1];

        compute_store(base, U0a, U0b, V0a, V0b);
        issue(sc0, dc0, U0a, U0b, V0a, V0b);

        compute_store(base + 1, U1a, U1b, V1a, V1b);
        issue(sc1, dc1, U1a, U1b, V1a, V1b);

        sc0 = sn0; dc0 = dn0; sc1 = sn1; dc1 = dn1;
    }
}

// ---------------- bucketing passes (2-D counting sort, 64 buckets) --------
// bucket(e) = slice(src)*8 + slice(dst), slice(i) = umulhi(i, mul8) ~ i*8/n.
#define NCH 2048

__global__ __launch_bounds__(256) void hist_k(
    const int* __restrict__ src, const int* __restrict__ dst,
    unsigned* __restrict__ counts, int E, int CH, unsigned mul8)
{
    __shared__ unsigned h[64];
    const int b = blockIdx.x;
    for (int i = threadIdx.x; i < 64; i += 256) h[i] = 0u;
    __syncthreads();
    const int lo = b * CH;
    int hi = lo + CH; if (hi > E) hi = E;
    for (int i = lo + threadIdx.x; i < hi; i += 256) {
        unsigned s = (unsigned)src[i], d = (unsigned)dst[i];
        unsigned bk = __umulhi(s, mul8) * 8u + __umulhi(d, mul8);
        atomicAdd(&h[bk], 1u);
    }
    __syncthreads();
    for (int i = threadIdx.x; i < 64; i += 256) counts[(size_t)b * 64 + i] = h[i];
}

// per-bucket exclusive scan over NCH chunk counts (64 blocks, one per bucket)
__global__ __launch_bounds__(256) void scanb_k(
    unsigned* __restrict__ counts, unsigned* __restrict__ totals)
{
    __shared__ unsigned part[256];
    const int bk = blockIdx.x;
    const int t  = threadIdx.x;
    unsigned vpre[8];
    unsigned sum = 0u;
    const int c0 = t * 8;
    #pragma unroll
    for (int j = 0; j < 8; ++j) {
        unsigned x = counts[(size_t)(c0 + j) * 64 + bk];
        vpre[j] = sum; sum += x;
    }
    part[t] = sum;
    __syncthreads();
    for (int d = 1; d < 256; d <<= 1) {
        unsigned x = (t >= d) ? part[t - d] : 0u;
        __syncthreads();
        part[t] += x;
        __syncthreads();
    }
    const unsigned incl = part[t];
    const unsigned excl = incl - sum;
    #pragma unroll
    for (int j = 0; j < 8; ++j)
        counts[(size_t)(c0 + j) * 64 + bk] = vpre[j] + excl;
    if (t == 255) totals[bk] = incl;
}

// exclusive scan of 64 bucket totals -> base[0..64]
__global__ __launch_bounds__(64) void base_k(
    const unsigned* __restrict__ totals, unsigned* __restrict__ base)
{
    const int t = threadIdx.x;
    const unsigned own = totals[t];
    unsigned x = own;
    #pragma unroll
    for (int d = 1; d < 64; d <<= 1) {
        unsigned y = __shfl_up(x, d, 64);
        if (t >= d) x += y;
    }
    base[t] = x - own;
    if (t == 63) base[64] = x;
}

__global__ __launch_bounds__(256) void scat_k(
    const int* __restrict__ src, const int* __restrict__ dst,
    const unsigned* __restrict__ counts, const unsigned* __restrict__ base,
    unsigned long long* __restrict__ recs, int E, int CH, unsigned mul8)
{
    __shared__ unsigned cur[64];
    const int b = blockIdx.x;
    for (int i = threadIdx.x; i < 64; i += 256)
        cur[i] = base[i] + counts[(size_t)b * 64 + i];
    __syncthreads();
    const int lo = b * CH;
    int hi = lo + CH; if (hi > E) hi = E;
    for (int i = lo + threadIdx.x; i < hi; i += 256) {
        unsigned s = (unsigned)src[i], d = (unsigned)dst[i];
        unsigned bk = __umulhi(s, mul8) * 8u + __umulhi(d, mul8);
        unsigned slot = atomicAdd(&cur[bk], 1u);
        recs[slot] = (unsigned long long)s
                   | ((unsigned long long)d << 17)
                   | ((unsigned long long)(unsigned)i << 34);
    }
}

// ---------------- K2: per-edge MLP over bucketed records ----------------
// XCD x (= bid&7) processes the contiguous record range of src-slice x:
// its 1.6MB u-slice stays L2-resident; v-slices stream through in order.
__global__ __launch_bounds__(256) void edge_mlp_b(
    const _Float16* __restrict__ u, const _Float16* __restrict__ v,
    const unsigned long long* __restrict__ recs,
    const unsigned* __restrict__ boff,
    const float* __restrict__ W2, const float* __restrict__ b2,
    const float* __restrict__ W3, const float* __restrict__ b3,
    float* __restrict__ out)
{
    const int lane = threadIdx.x & 63;
    const int q = lane >> 4;
    const int c = lane & 15;

    const int x   = blockIdx.x & 7;
    const int lb  = blockIdx.x >> 3;
    const int nlb = gridDim.x >> 3;

    const unsigned rs = boff[x * 8];
    const unsigned re = boff[x * 8 + 8];
    if (re <= rs) return;
    const int ntiles = (int)((re - rs + 15u) >> 4);

    half8 Af[4][2];
    #pragma unroll
    for (int t = 0; t < 4; ++t)
        #pragma unroll
        for (int ks = 0; ks < 2; ++ks)
            #pragma unroll
            for (int j = 0; j < 8; ++j) {
                int k = ks * 32 + q * 8 + j;
                Af[t][ks][j] = (_Float16)W2[k * HD + t * 16 + c];
            }
    f32x4 b2q[4], w3q[4];
    #pragma unroll
    for (int t = 0; t < 4; ++t) {
        b2q[t] = *(const f32x4*)(b2 + t * 16 + q * 4);
        w3q[t] = *(const f32x4*)(W3 + t * 16 + q * 4);
    }
    const float b3v = b3[0];

    const int wid = lb * ((int)blockDim.x >> 6) + (threadIdx.x >> 6);
    const int nw  = nlb * ((int)blockDim.x >> 6);
    const int stride = nw * 2;
    const int base0  = wid * 2;
    if (base0 >= ntiles) return;

    auto ridx = [&](int tile) -> unsigned {
        int t = tile; if (t >= ntiles) t = ntiles - 1;
        unsigned r = rs + (unsigned)t * 16u + (unsigned)c;
        if (r >= re) r = re - 1u;
        return r;
    };
    auto issue = [&](unsigned s, unsigned d, half8& Ua, half8& Ub, half8& Va, half8& Vb) {
        const half8* up = (const half8*)(u + (unsigned)s * HD + q * 8);
        const half8* vp = (const half8*)(v + (unsigned)d * HD + q * 8);
        Ua = up[0]; Ub = up[4]; Va = vp[0]; Vb = vp[4];
    };
    auto compute_store = [&](int tile, unsigned eid,
                             half8 Ua, half8 Ub, half8 Va, half8 Vb) {
        half8 B0 = relu_h8(Ua + Va);
        half8 B1 = relu_h8(Ub + Vb);
        f32x4 acc[4];
        #pragma unroll
        for (int t = 0; t < 4; ++t) acc[t] = b2q[t];   // b2 via MFMA C-in
        #pragma unroll
        for (int t = 0; t < 4; ++t) {
            acc[t] = __builtin_amdgcn_mfma_f32_16x16x32_f16(Af[t][0], B0, acc[t], 0, 0, 0);
            acc[t] = __builtin_amdgcn_mfma_f32_16x16x32_f16(Af[t][1], B1, acc[t], 0, 0, 0);
        }
        float p = 0.f;
        #pragma unroll
        for (int t = 0; t < 4; ++t)
            #pragma unroll
            for (int r = 0; r < 4; ++r)
                p = fmaf(fmaxf(acc[t][r], 0.f), w3q[t][r], p);
        p += __shfl_xor(p, 16, 64);
        p += __shfl_xor(p, 32, 64);
        if (q == 0 && (rs + (unsigned)tile * 16u + (unsigned)c) < re)
            out[eid] = p + b3v;
    };

    // ---- prologue (rec prefetch one full iteration ahead, vmcnt-friendly) ----
    unsigned long long r0 = recs[ridx(base0)];
    unsigned long long r1 = recs[ridx(base0 + 1)];
    unsigned e0 = (unsigned)(r0 >> 34);
    unsigned e1 = (unsigned)(r1 >> 34);
    half8 U0a, U0b, V0a, V0b, U1a, U1b, V1a, V1b;
    issue((unsigned)r0 & 0x1FFFFu, (unsigned)(r0 >> 17) & 0x1FFFFu, U0a, U0b, V0a, V0b);
    issue((unsigned)r1 & 0x1FFFFu, (unsigned)(r1 >> 17) & 0x1FFFFu, U1a, U1b, V1a, V1b);
    unsigned long long rc0 = recs[ridx(base0 + stride)];
    unsigned long long rc1 = recs[ridx(base0 + stride + 1)];

    for (int bse = base0; bse < ntiles; bse += stride) {
        const unsigned long long rn0 = recs[ridx(bse + 2 * stride)];
        const unsigned long long rn1 = recs[ridx(bse + 2 * stride + 1)];

        compute_store(bse, e0, U0a, U0b, V0a, V0b);
        e0 = (unsigned)(rc0 >> 34);
        issue((unsigned)rc0 & 0x1FFFFu, (unsigned)(rc0 >> 17) & 0x1FFFFu,
              U0a, U0b, V0a, V0b);

        compute_store(bse + 1, e1, U1a, U1b, V1a, V1b);
        e1 = (unsigned)(rc1 >> 34);
        issue((unsigned)rc1 & 0x1FFFFu, (unsigned)(rc1 >> 17) & 0x1FFFFu,
              U1a, U1b, V1a, V1b);

        rc0 = rn0; rc1 = rn1;
    }
}

extern "C" void kernel_launch(void* const* d_in, const int* in_sizes, int n_in,
                              void* d_out, int out_size, void* d_ws, size_t ws_size,
                              hipStream_t stream) {
    const float* emb  = (const float*)d_in[0];
    const float* fied = (const float*)d_in[1];
    const float* W1   = (const float*)d_in[2];
    const float* b1   = (const float*)d_in[3];
    const float* W2   = (const float*)d_in[4];
    const float* b2   = (const float*)d_in[5];
    const float* W3   = (const float*)d_in[6];
    const float* b3   = (const float*)d_in[7];
    const int*   eidx = (const int*)d_in[8];

    const int n_nodes = in_sizes[1];
    const int E       = in_sizes[8] / 2;
    const int* srcp = eidx;
    const int* dstp = eidx + E;

    _Float16* u = (_Float16*)d_ws;                 // n_nodes*64 fp16
    _Float16* v = u + (size_t)n_nodes * HD;        // n_nodes*64 fp16
    const size_t uv_bytes = (size_t)n_nodes * HD * 2 * sizeof(_Float16);

    const int ntilesN = (n_nodes + 15) / 16;
    precompute_uv<<<1024, 256, 0, stream>>>(emb, fied, W1, b1, u, v,
                                            n_nodes, ntilesN);

    // workspace layout for bucketed path
    const size_t recs_off   = uv_bytes;
    const size_t counts_off = recs_off + (size_t)E * 8;
    const size_t totals_off = counts_off + (size_t)NCH * 64 * 4;
    const size_t base_off   = totals_off + 64 * 4;
    const size_t need       = base_off + 65 * 4;

    const bool can_bucket = (ws_size >= need) &&
                            (n_nodes <= 131072) && (n_nodes >= 4096) &&
                            ((long long)E < (1LL << 30));

    if (can_bucket) {
        unsigned long long* recs = (unsigned long long*)((char*)d_ws + recs_off);
        unsigned* counts = (unsigned*)((char*)d_ws + counts_off);
        unsigned* totals = (unsigned*)((char*)d_ws + totals_off);
        unsigned* basep  = (unsigned*)((char*)d_ws + base_off);
        const unsigned mul8 = (unsigned)((8ULL << 32) / (unsigned long long)n_nodes);
        const int CH = (E + NCH - 1) / NCH;

        hist_k <<<NCH, 256, 0, stream>>>(srcp, dstp, counts, E, CH, mul8);
        scanb_k<<<64,  256, 0, stream>>>(counts, totals);
        base_k <<<1,    64, 0, stream>>>(totals, basep);
        scat_k <<<NCH, 256, 0, stream>>>(srcp, dstp, counts, basep, recs, E, CH, mul8);
        edge_mlp_b<<<2048, 256, 0, stream>>>(u, v, recs, basep,
                                             W2, b2, W3, b3, (float*)d_out);
    } else {
        const int ntilesE = (E + 15) / 16;
        edge_mlp<<<2048, 256, 0, stream>>>(u, v, srcp, dstp, W2, b2, W3, b3,
                                           (float*)d_out, E, ntilesE);
    }
}